// Round 8
// baseline (17610.580 us; speedup 1.0000x reference)
//
#include <hip/hip_runtime.h>

// Pendulum 3-layer LSTM (H=128), B=256 rows, 1024 sequential steps.
// Head collapsed to y = weff.h3 + beff (exact fp32 precompute).
//
// ROUND 8: TLP. 128 blocks x 1024 threads (16 waves = 4 waves/SIMD), 2 rows.
// Thread = (idx in 128, kq in 8). Rounds 3-7 plateaued at 10-13ms because
// only 2 waves/SIMD left ~85% of each step as unhidden L2 latency.
//   - Whh1 (128KB) LDS-resident, stream-order [slot][tid] (contiguous reads).
//   - L2+L3 weights (512KB) stream L2->reg via 8-slot ring (32 VGPRs),
//     consumption-order pack, consume-then-refill, counted vmcnt survives
//     barriers. 4-way wave interleave hides refill latency.
//   - 3 barriers/step cross-step pipeline (verbatim semantics from round 5).

typedef _Float16 f16;
typedef _Float16 f16x2 __attribute__((ext_vector_type(2)));
typedef unsigned int u32;

#define T_IN 512
#define T_TOT 1024
#define NBLK 128

__device__ __forceinline__ f16x2 u2h(u32 u) { return __builtin_bit_cast(f16x2, u); }

__device__ __forceinline__ float fdot2f(f16x2 a, f16x2 b, float c) {
#if __has_builtin(__builtin_amdgcn_fdot2)
  return __builtin_amdgcn_fdot2(a, b, c, false);
#else
  return c + (float)a[0] * (float)b[0] + (float)a[1] * (float)b[1];
#endif
}

__device__ __forceinline__ float frcp(float x) {
#if __has_builtin(__builtin_amdgcn_rcpf)
  return __builtin_amdgcn_rcpf(x);
#else
  return 1.f / x;
#endif
}
__device__ __forceinline__ float fsigm(float x) { return frcp(1.f + __expf(-x)); }
__device__ __forceinline__ float ftanh(float x) { return 1.f - 2.f * frcp(1.f + __expf(2.f * x)); }

#define DOT4(acc, w, hv)                     \
  do {                                       \
    f16x2 _h = u2h(hv);                      \
    acc[0] = fdot2f(u2h((w).x), _h, acc[0]); \
    acc[1] = fdot2f(u2h((w).y), _h, acc[1]); \
    acc[2] = fdot2f(u2h((w).z), _h, acc[2]); \
    acc[3] = fdot2f(u2h((w).w), _h, acc[3]); \
  } while (0)

// ---- weight packing -------------------------------------------------------
// Combined L2+L3 stream, consumption order. 32 slots x 1024 thread-cols x u4.
// Thread col t: idx = t>>3, kq = t&7.
//  s<24: q=s/3, r=s%3:
//    r<2:  L2 pair p = kq*16 + 2q + r over [Wih2|Whh2] (K=[h1_new|h2_old])
//    r==2: L3-early pair p = kq*8 + q over Whh3 (K=h3_old)
//  s>=24: L3-late pair p = kq*8 + (s-24) over Wih3 (K=h2_new)
// u4 slot g holds half2{ W[g*128+idx][2p], W[g*128+idx][2p+1] } (gates i,f,g,o).
__global__ void pack_stream(u32* dst, const float* Wih2, const float* Whh2,
                            const float* Wih3, const float* Whh3) {
  int tid = blockIdx.x * 256 + threadIdx.x;
  if (tid >= 32 * 1024 * 4) return;
  int g = tid & 3;
  int t = (tid >> 2) & 1023;
  int s = tid >> 12;
  int idx = t >> 3, kq = t & 7;
  const float* src;
  int p;
  if (s < 24) {
    int q = s / 3, r = s % 3;
    if (r < 2) {
      p = kq * 16 + 2 * q + r;
      if (p < 64) { src = Wih2; } else { src = Whh2; p -= 64; }
    } else {
      p = kq * 8 + q;
      src = Whh3;
    }
  } else {
    p = kq * 8 + (s - 24);
    src = Wih3;
  }
  int j = g * 128 + idx;
  union { f16 h[2]; u32 u; } cv;
  cv.h[0] = (f16)src[j * 128 + 2 * p];
  cv.h[1] = (f16)src[j * 128 + 2 * p + 1];
  dst[tid] = cv.u;
}

// Whh1 stream-order LDS image: slot sl in [0,8): pair p = kq*8 + sl.
__global__ void pack1s(u32* dst, const float* Whh1) {
  int tid = blockIdx.x * 256 + threadIdx.x;
  if (tid >= 8 * 1024 * 4) return;
  int g = tid & 3;
  int t = (tid >> 2) & 1023;
  int sl = tid >> 12;
  int idx = t >> 3, kq = t & 7;
  int p = kq * 8 + sl;
  int j = g * 128 + idx;
  union { f16 h[2]; u32 u; } cv;
  cv.h[0] = (f16)Whh1[j * 128 + 2 * p];
  cv.h[1] = (f16)Whh1[j * 128 + 2 * p + 1];
  dst[tid] = cv.u;
}

// consT[gg*512 + g*128 + idx]: gg 0=b1,1=b2,2=b3,3=wih1. [2048+idx]=weff, [2176]=beff.
__global__ void prep_cons(float* cons, const float* a1, const float* b1,
                          const float* a2, const float* b2,
                          const float* a3, const float* b3, const float* wih1) {
  int tid = blockIdx.x * 256 + threadIdx.x;
  if (tid >= 2048) return;
  int gg = tid >> 9, g = (tid >> 7) & 3, idx = tid & 127;
  int j = g * 128 + idx;
  float v;
  if (gg == 0) v = a1[j] + b1[j];
  else if (gg == 1) v = a2[j] + b2[j];
  else if (gg == 2) v = a3[j] + b3[j];
  else v = wih1[j];
  cons[tid] = v;
}

__global__ void head_fold(float* cons, const float* lin_w, const float* out_w,
                          const float* Wv, const float* bv,
                          const float* out_b, const float* lin_b) {
  __shared__ float wlo[128];
  __shared__ float pr[128];
  int j = threadIdx.x;
  float s = 0.f;
  for (int k = 0; k < 128; ++k) s += lin_w[k] * out_w[k * 128 + j];
  wlo[j] = s;
  __syncthreads();
  float t = 0.f;
  for (int k = 0; k < 128; ++k) t += wlo[k] * Wv[k * 128 + j];
  cons[2048 + j] = t;
  pr[j] = s * bv[j] + lin_w[j] * out_b[j];
  __syncthreads();
  if (j == 0) {
    float b = lin_b[0];
    for (int k = 0; k < 128; ++k) b += pr[k];
    cons[2176] = b;
  }
}

// ---- main persistent kernel ----------------------------------------------
__global__ __launch_bounds__(1024, 1) void pendulum_persist(
    const float* __restrict__ input, const uint4* __restrict__ W1g,
    const uint4* __restrict__ WS, const float* __restrict__ consG,
    float* __restrict__ out) {
  __shared__ __align__(16) uint4 w1s[8192];     // 128 KB stream-order Whh1
  __shared__ __align__(16) f16 h1b[2][2][128];  // [parity][row][idx]
  __shared__ __align__(16) f16 h2b[2][2][128];
  __shared__ __align__(16) f16 h3b[2][128];     // [row][idx]
  __shared__ float consL[2180];
  __shared__ float redp[2][16];

  const int t = threadIdx.x;
  const int idx = t >> 3;  // hidden unit
  const int kq = t & 7;    // K-eighth
  const int row0 = blockIdx.x * 2, row1 = row0 + 1;

  for (int e = t; e < 8192; e += 1024) w1s[e] = W1g[e];
  for (int e = t; e < 2177; e += 1024) consL[e] = consG[e];
  if (t < 128) {
    h1b[0][0][t] = (f16)0.f; h1b[0][1][t] = (f16)0.f;
    h1b[1][0][t] = (f16)0.f; h1b[1][1][t] = (f16)0.f;
    h2b[0][0][t] = (f16)0.f; h2b[0][1][t] = (f16)0.f;
    h2b[1][0][t] = (f16)0.f; h2b[1][1][t] = (f16)0.f;
    h3b[0][t] = (f16)0.f;    h3b[1][t] = (f16)0.f;
  }

  const uint4* Wp = WS + t;
  const uint4* w1p = w1s + t;

  float c1a = 0.f, c1b = 0.f, c2a = 0.f, c2b = 0.f, c3a = 0.f, c3b = 0.f;
  float y0 = 0.f, y1 = 0.f;
  __syncthreads();
  const float beffv = consL[2176];

  // prologue: step-0 layer1 (h1_old = 0 -> no dots)
  {
    float x0 = input[row0 * T_IN], x1 = input[row1 * T_IN];
    if (kq == 0) {
      float b0 = consL[idx], b2v = consL[256 + idx], b3v = consL[384 + idx];
      float w0 = consL[1536 + idx], w2w = consL[1792 + idx],
            w3w = consL[1920 + idx];
      {
        float ig = fsigm(b0 + x0 * w0);
        float gg = ftanh(b2v + x0 * w2w), og = fsigm(b3v + x0 * w3w);
        c1a = ig * gg; h1b[0][0][idx] = (f16)(og * ftanh(c1a));
      }
      {
        float ig = fsigm(b0 + x1 * w0);
        float gg = ftanh(b2v + x1 * w2w), og = fsigm(b3v + x1 * w3w);
        c1b = ig * gg; h1b[0][1][idx] = (f16)(og * ftanh(c1b));
      }
    }
    __syncthreads();
  }

  // ring prologue: slots 0..7
  uint4 ring[8];
#pragma unroll
  for (int c = 0; c < 8; ++c) ring[c] = Wp[c * 1024];

  for (int s = 0; s < T_TOT; ++s) {
    const int par = s & 1;
    const int xi = (s + 1 < T_IN) ? (s + 1) : 0;
    float xl0 = input[row0 * T_IN + xi];
    float xl1 = input[row1 * T_IN + xi];

    // ---- P_A: L2 dots (16 u4/thread) + L3-early dots (8 u4/thread) ----
    const uint4* hA0 = (kq < 4)
        ? (const uint4*)&h1b[par][0][0] + kq * 4
        : (const uint4*)&h2b[par ^ 1][0][0] + (kq - 4) * 4;
    const uint4* hA1 = (kq < 4)
        ? (const uint4*)&h1b[par][1][0] + kq * 4
        : (const uint4*)&h2b[par ^ 1][1][0] + (kq - 4) * 4;
    const uint4* e3p0 = (const uint4*)&h3b[0][0] + kq * 2;
    const uint4* e3p1 = (const uint4*)&h3b[1][0] + kq * 2;

    float a2r0[4] = {0, 0, 0, 0}, a2r1[4] = {0, 0, 0, 0};
    float a3r0[4] = {0, 0, 0, 0}, a3r1[4] = {0, 0, 0, 0};
    uint4 H0, H1, E0, E1;
#pragma unroll
    for (int q8 = 0; q8 < 8; ++q8) {
      if ((q8 & 1) == 0) { H0 = hA0[q8 >> 1]; H1 = hA1[q8 >> 1]; }
      if ((q8 & 3) == 0) { E0 = e3p0[q8 >> 2]; E1 = e3p1[q8 >> 2]; }
      u32 h0a[4] = {H0.x, H0.y, H0.z, H0.w};
      u32 h1a[4] = {H1.x, H1.y, H1.z, H1.w};
      u32 e0a[4] = {E0.x, E0.y, E0.z, E0.w};
      u32 e1a[4] = {E1.x, E1.y, E1.z, E1.w};
#pragma unroll
      for (int r = 0; r < 2; ++r) {
        const int sl = 3 * q8 + r;
        uint4 w = ring[sl & 7];
        ring[sl & 7] = Wp[((sl + 8) & 31) * 1024];
        const int hi = 2 * (q8 & 1) + r;
        DOT4(a2r0, w, h0a[hi]);
        DOT4(a2r1, w, h1a[hi]);
      }
      {
        const int sl = 3 * q8 + 2;
        uint4 w = ring[sl & 7];
        ring[sl & 7] = Wp[((sl + 8) & 31) * 1024];
        DOT4(a3r0, w, e0a[q8 & 3]);
        DOT4(a3r1, w, e1a[q8 & 3]);
      }
    }

    // L2 finish (8-way kq reduce)
#pragma unroll
    for (int g = 0; g < 4; ++g) {
      a2r0[g] += __shfl_xor(a2r0[g], 1, 64);
      a2r0[g] += __shfl_xor(a2r0[g], 2, 64);
      a2r0[g] += __shfl_xor(a2r0[g], 4, 64);
      a2r1[g] += __shfl_xor(a2r1[g], 1, 64);
      a2r1[g] += __shfl_xor(a2r1[g], 2, 64);
      a2r1[g] += __shfl_xor(a2r1[g], 4, 64);
    }
    if (kq == 0) {
      float b0 = consL[512 + idx], b1v = consL[640 + idx],
            b2v = consL[768 + idx], b3v = consL[896 + idx];
      {
        float ig = fsigm(a2r0[0] + b0), fg = fsigm(a2r0[1] + b1v);
        float gg = ftanh(a2r0[2] + b2v), og = fsigm(a2r0[3] + b3v);
        c2a = fg * c2a + ig * gg;
        h2b[par][0][idx] = (f16)(og * ftanh(c2a));
      }
      {
        float ig = fsigm(a2r1[0] + b0), fg = fsigm(a2r1[1] + b1v);
        float gg = ftanh(a2r1[2] + b2v), og = fsigm(a2r1[3] + b3v);
        c2b = fg * c2b + ig * gg;
        h2b[par][1][idx] = (f16)(og * ftanh(c2b));
      }
    }
    asm volatile("s_waitcnt lgkmcnt(0)\n\ts_barrier" ::: "memory");  // barrier1

    // ---- P_B: L3-late (8 u4, ring) + L1 dots for step s+1 (8 u4, LDS) ----
    const uint4* hB0 = (const uint4*)&h2b[par][0][0] + kq * 2;
    const uint4* hB1 = (const uint4*)&h2b[par][1][0] + kq * 2;
    const uint4* f0p = (const uint4*)&h1b[par][0][0] + kq * 2;
    const uint4* f1p = (const uint4*)&h1b[par][1][0] + kq * 2;

    float a1r0[4] = {0, 0, 0, 0}, a1r1[4] = {0, 0, 0, 0};
    uint4 L0, L1v, F0, F1;
#pragma unroll
    for (int j = 0; j < 8; ++j) {
      if ((j & 3) == 0) {
        L0 = hB0[j >> 2]; L1v = hB1[j >> 2];
        F0 = f0p[j >> 2]; F1 = f1p[j >> 2];
      }
      u32 l0a[4] = {L0.x, L0.y, L0.z, L0.w};
      u32 l1a[4] = {L1v.x, L1v.y, L1v.z, L1v.w};
      u32 fa0[4] = {F0.x, F0.y, F0.z, F0.w};
      u32 fa1[4] = {F1.x, F1.y, F1.z, F1.w};
      {
        const int sl = 24 + j;
        uint4 w = ring[sl & 7];
        ring[sl & 7] = Wp[((sl + 8) & 31) * 1024];
        DOT4(a3r0, w, l0a[j & 3]);
        DOT4(a3r1, w, l1a[j & 3]);
      }
      {
        uint4 w = w1p[j * 1024];
        DOT4(a1r0, w, fa0[j & 3]);
        DOT4(a1r1, w, fa1[j & 3]);
      }
    }

#pragma unroll
    for (int g = 0; g < 4; ++g) {
      a3r0[g] += __shfl_xor(a3r0[g], 1, 64);
      a3r0[g] += __shfl_xor(a3r0[g], 2, 64);
      a3r0[g] += __shfl_xor(a3r0[g], 4, 64);
      a3r1[g] += __shfl_xor(a3r1[g], 1, 64);
      a3r1[g] += __shfl_xor(a3r1[g], 2, 64);
      a3r1[g] += __shfl_xor(a3r1[g], 4, 64);
      a1r0[g] += __shfl_xor(a1r0[g], 1, 64);
      a1r0[g] += __shfl_xor(a1r0[g], 2, 64);
      a1r0[g] += __shfl_xor(a1r0[g], 4, 64);
      a1r1[g] += __shfl_xor(a1r1[g], 1, 64);
      a1r1[g] += __shfl_xor(a1r1[g], 2, 64);
      a1r1[g] += __shfl_xor(a1r1[g], 4, 64);
    }

    // L3 finish + head partial
    float p0 = 0.f, p1 = 0.f;
    if (kq == 0) {
      float b0 = consL[1024 + idx], b1v = consL[1152 + idx],
            b2v = consL[1280 + idx], b3v = consL[1408 + idx];
      float weffr = consL[2048 + idx];
      {
        float ig = fsigm(a3r0[0] + b0), fg = fsigm(a3r0[1] + b1v);
        float gg = ftanh(a3r0[2] + b2v), og = fsigm(a3r0[3] + b3v);
        c3a = fg * c3a + ig * gg;
        float h3 = og * ftanh(c3a);
        h3b[0][idx] = (f16)h3;
        p0 = weffr * h3;
      }
      {
        float ig = fsigm(a3r1[0] + b0), fg = fsigm(a3r1[1] + b1v);
        float gg = ftanh(a3r1[2] + b2v), og = fsigm(a3r1[3] + b3v);
        c3b = fg * c3b + ig * gg;
        float h3 = og * ftanh(c3b);
        h3b[1][idx] = (f16)h3;
        p1 = weffr * h3;
      }
    }
#pragma unroll
    for (int k = 1; k < 64; k <<= 1) {
      p0 += __shfl_xor(p0, k, 64);
      p1 += __shfl_xor(p1, k, 64);
    }
    if ((t & 63) == 0) { redp[0][t >> 6] = p0; redp[1][t >> 6] = p1; }
    asm volatile("s_waitcnt lgkmcnt(0)\n\ts_barrier" ::: "memory");  // barrier2

    y0 = beffv; y1 = beffv;
#pragma unroll
    for (int w16 = 0; w16 < 16; ++w16) { y0 += redp[0][w16]; y1 += redp[1][w16]; }
    if (t == 0) out[row0 * T_TOT + s] = y0;
    else if (t == 1) out[row1 * T_TOT + s] = y1;

    // L1 finish for step s+1
    float xv0 = (s + 1 < T_IN) ? xl0 : y0;
    float xv1 = (s + 1 < T_IN) ? xl1 : y1;
    if (kq == 0) {
      float b0 = consL[idx], b1v = consL[128 + idx], b2v = consL[256 + idx],
            b3v = consL[384 + idx];
      float w0 = consL[1536 + idx], w1w = consL[1664 + idx],
            w2w = consL[1792 + idx], w3w = consL[1920 + idx];
      {
        float ig = fsigm(a1r0[0] + b0 + xv0 * w0), fg = fsigm(a1r0[1] + b1v + xv0 * w1w);
        float gg = ftanh(a1r0[2] + b2v + xv0 * w2w), og = fsigm(a1r0[3] + b3v + xv0 * w3w);
        c1a = fg * c1a + ig * gg;
        h1b[par ^ 1][0][idx] = (f16)(og * ftanh(c1a));
      }
      {
        float ig = fsigm(a1r1[0] + b0 + xv1 * w0), fg = fsigm(a1r1[1] + b1v + xv1 * w1w);
        float gg = ftanh(a1r1[2] + b2v + xv1 * w2w), og = fsigm(a1r1[3] + b3v + xv1 * w3w);
        c1b = fg * c1b + ig * gg;
        h1b[par ^ 1][1][idx] = (f16)(og * ftanh(c1b));
      }
    }
    asm volatile("s_waitcnt lgkmcnt(0)\n\ts_barrier" ::: "memory");  // barrier3
  }
}

// ---- launch ---------------------------------------------------------------
extern "C" void kernel_launch(void* const* d_in, const int* in_sizes, int n_in,
                              void* d_out, int out_size, void* d_ws, size_t ws_size,
                              hipStream_t stream) {
  const float* input = (const float*)d_in[0];
  const float* Wih1 = (const float*)d_in[2];
  const float* Whh1 = (const float*)d_in[3];
  const float* bih1 = (const float*)d_in[4];
  const float* bhh1 = (const float*)d_in[5];
  const float* Wih2 = (const float*)d_in[6];
  const float* Whh2 = (const float*)d_in[7];
  const float* bih2 = (const float*)d_in[8];
  const float* bhh2 = (const float*)d_in[9];
  const float* Wih3 = (const float*)d_in[10];
  const float* Whh3 = (const float*)d_in[11];
  const float* bih3 = (const float*)d_in[12];
  const float* bhh3 = (const float*)d_in[13];
  const float* in_proj_w = (const float*)d_in[14];
  const float* in_proj_b = (const float*)d_in[15];
  const float* out_w = (const float*)d_in[16];
  const float* out_b = (const float*)d_in[17];
  const float* lin_w = (const float*)d_in[18];
  const float* lin_b = (const float*)d_in[19];

  char* ws = (char*)d_ws;
  u32* W1g = (u32*)(ws + (0 << 10));    // 128 KB stream-order Whh1 (LDS image)
  u32* WS = (u32*)(ws + (128 << 10));   // 512 KB combined L2+L3 stream
  float* consG = (float*)(ws + (640 << 10));  // ~8.7 KB

  pack1s<<<128, 256, 0, stream>>>(W1g, Whh1);
  pack_stream<<<512, 256, 0, stream>>>(WS, Wih2, Whh2, Wih3, Whh3);
  prep_cons<<<8, 256, 0, stream>>>(consG, bih1, bhh1, bih2, bhh2, bih3, bhh3, Wih1);
  head_fold<<<1, 128, 0, stream>>>(consG, lin_w, out_w,
                                   in_proj_w + 2 * 128 * 128, in_proj_b + 256,
                                   out_b, lin_b);

  pendulum_persist<<<NBLK, 1024, 0, stream>>>(
      input, (const uint4*)W1g, (const uint4*)WS, consG, (float*)d_out);
}

// Round 9
// 9068.517 us; speedup vs baseline: 1.9419x; 1.9419x over previous
//
#include <hip/hip_runtime.h>

// Pendulum 3-layer LSTM (H=128), B=256 rows, 1024 sequential steps.
// Head collapsed to y = weff.h3 + beff (exact fp32 precompute).
// 128 blocks x 512 threads, 2 rows/block. Thread = (idx in 128, kq in 4).
//
// ROUND 9: spill elimination. Rounds 4-8 root cause: register demand above
// the allocator's per-wave budget -> scratch spills on the serial path ->
// spill traffic also evicts weights from L2 (FETCH 415MB..22GB).
//   - ring 16 -> 8 slots (32 VGPRs): hot-loop live regs ~100 < 128.
//   - amdgpu_waves_per_eu(2): the real occupancy-target knob (256-reg cap),
//     launch_bounds' 2nd arg was ignored.
//   - Everything else verbatim from round 7 (passed, absmax 2.4e-4):
//     consumption-order L2+L3 stream (64 slots/step), stream-order L1 in LDS,
//     3-barrier cross-step pipeline.

typedef _Float16 f16;
typedef _Float16 f16x2 __attribute__((ext_vector_type(2)));
typedef unsigned int u32;

#define T_IN 512
#define T_TOT 1024
#define NBLK 128

__device__ __forceinline__ f16x2 u2h(u32 u) { return __builtin_bit_cast(f16x2, u); }

__device__ __forceinline__ float fdot2f(f16x2 a, f16x2 b, float c) {
#if __has_builtin(__builtin_amdgcn_fdot2)
  return __builtin_amdgcn_fdot2(a, b, c, false);
#else
  return c + (float)a[0] * (float)b[0] + (float)a[1] * (float)b[1];
#endif
}

__device__ __forceinline__ float frcp(float x) {
#if __has_builtin(__builtin_amdgcn_rcpf)
  return __builtin_amdgcn_rcpf(x);
#else
  return 1.f / x;
#endif
}
__device__ __forceinline__ float fsigm(float x) { return frcp(1.f + __expf(-x)); }
__device__ __forceinline__ float ftanh(float x) { return 1.f - 2.f * frcp(1.f + __expf(2.f * x)); }

#define DOT4(acc, w, hv)                     \
  do {                                       \
    f16x2 _h = u2h(hv);                      \
    acc[0] = fdot2f(u2h((w).x), _h, acc[0]); \
    acc[1] = fdot2f(u2h((w).y), _h, acc[1]); \
    acc[2] = fdot2f(u2h((w).z), _h, acc[2]); \
    acc[3] = fdot2f(u2h((w).w), _h, acc[3]); \
  } while (0)

// ---- weight packing -------------------------------------------------------
// Combined L2+L3 stream, consumption order. 64 slots x 512 thread-cols x u4.
// Thread col t = idx*4+kq. Slot map:
//  s<48 (P_A, q=s/6, rmd=s%6):
//    rmd<4:  L2 pair p = kq*32 + 4q + rmd over [Wih2|Whh2] (K=[h1_new|h2_old])
//    rmd>=4: L3-early pair i = 2q+(rmd-4); Whh3 col pair kq*16+i (K=h3_old)
//  s>=48:    L3-late  pair u = s-48;      Wih3 col pair kq*16+u (K=h2_new)
// u4 slot g holds half2{ W[g*128+idx][2p], W[g*128+idx][2p+1] }.
__global__ void pack_stream(u32* dst, const float* Wih2, const float* Whh2,
                            const float* Wih3, const float* Whh3) {
  int tid = blockIdx.x * 256 + threadIdx.x;
  if (tid >= 64 * 512 * 4) return;
  int g = tid & 3;
  int t = (tid >> 2) & 511;
  int s = tid >> 11;
  int idx = t >> 2, kq = t & 3;
  const float* src;
  int p;
  if (s < 48) {
    int q = s / 6, rmd = s % 6;
    if (rmd < 4) {
      p = kq * 32 + 4 * q + rmd;
      if (p < 64) { src = Wih2; } else { src = Whh2; p -= 64; }
    } else {
      p = kq * 16 + 2 * q + (rmd - 4);
      src = Whh3;
    }
  } else {
    p = kq * 16 + (s - 48);
    src = Wih3;
  }
  int j = g * 128 + idx;
  union { f16 h[2]; u32 u; } cv;
  cv.h[0] = (f16)src[j * 128 + 2 * p];
  cv.h[1] = (f16)src[j * 128 + 2 * p + 1];
  dst[tid] = cv.u;
}

// L1 (Whh1), stream order: w1s[q*512 + t], q in [0,16): pair p = kq*16+q.
__global__ void pack1s(u32* dst, const float* Whh1) {
  int tid = blockIdx.x * 256 + threadIdx.x;
  if (tid >= 16 * 512 * 4) return;
  int g = tid & 3;
  int t = (tid >> 2) & 511;
  int q = tid >> 11;
  int idx = t >> 2, kq = t & 3;
  int p = kq * 16 + q;
  int j = g * 128 + idx;
  union { f16 h[2]; u32 u; } cv;
  cv.h[0] = (f16)Whh1[j * 128 + 2 * p];
  cv.h[1] = (f16)Whh1[j * 128 + 2 * p + 1];
  dst[tid] = cv.u;
}

// consT[gg*512 + g*128 + idx]: gg 0=b1,1=b2,2=b3,3=wih1. [2048+idx]=weff, [2176]=beff.
__global__ void prep_cons(float* cons, const float* a1, const float* b1,
                          const float* a2, const float* b2,
                          const float* a3, const float* b3, const float* wih1) {
  int tid = blockIdx.x * 256 + threadIdx.x;
  if (tid >= 2048) return;
  int gg = tid >> 9, g = (tid >> 7) & 3, idx = tid & 127;
  int j = g * 128 + idx;
  float v;
  if (gg == 0) v = a1[j] + b1[j];
  else if (gg == 1) v = a2[j] + b2[j];
  else if (gg == 2) v = a3[j] + b3[j];
  else v = wih1[j];
  cons[tid] = v;
}

__global__ void head_fold(float* cons, const float* lin_w, const float* out_w,
                          const float* Wv, const float* bv,
                          const float* out_b, const float* lin_b) {
  __shared__ float wlo[128];
  __shared__ float pr[128];
  int j = threadIdx.x;
  float s = 0.f;
  for (int k = 0; k < 128; ++k) s += lin_w[k] * out_w[k * 128 + j];
  wlo[j] = s;
  __syncthreads();
  float t = 0.f;
  for (int k = 0; k < 128; ++k) t += wlo[k] * Wv[k * 128 + j];
  cons[2048 + j] = t;
  pr[j] = s * bv[j] + lin_w[j] * out_b[j];
  __syncthreads();
  if (j == 0) {
    float b = lin_b[0];
    for (int k = 0; k < 128; ++k) b += pr[k];
    cons[2176] = b;
  }
}

// ---- main persistent kernel ----------------------------------------------
__global__ __launch_bounds__(512)
__attribute__((amdgpu_waves_per_eu(2))) void pendulum_persist(
    const float* __restrict__ input, const uint4* __restrict__ WT1s,
    const uint4* __restrict__ WS, const float* __restrict__ consG,
    float* __restrict__ out) {
  __shared__ __align__(16) uint4 w1s[8192];     // 128 KB, stream-order L1
  __shared__ __align__(16) f16 h1b[2][2][128];  // [parity][row][idx]
  __shared__ __align__(16) f16 h2b[2][2][128];
  __shared__ __align__(16) f16 h3b[2][128];     // [row][idx], single buffer
  __shared__ float consL[2180];
  __shared__ float redp[2][8];

  const int t = threadIdx.x;
  const int idx = t >> 2;
  const int kq = t & 3;
  const int row0 = blockIdx.x * 2, row1 = row0 + 1;

  for (int e = t; e < 8192; e += 512) w1s[e] = WT1s[e];
  for (int e = t; e < 2177; e += 512) consL[e] = consG[e];
  if (t < 128) {
    h1b[0][0][t] = (f16)0.f; h1b[0][1][t] = (f16)0.f;
    h1b[1][0][t] = (f16)0.f; h1b[1][1][t] = (f16)0.f;
    h2b[0][0][t] = (f16)0.f; h2b[0][1][t] = (f16)0.f;
    h2b[1][0][t] = (f16)0.f; h2b[1][1][t] = (f16)0.f;
    h3b[0][t] = (f16)0.f;    h3b[1][t] = (f16)0.f;
  }

  const uint4* Wp = WS + t;
  const uint4* w1p = w1s + t;

  float c1a = 0.f, c1b = 0.f, c2a = 0.f, c2b = 0.f, c3a = 0.f, c3b = 0.f;
  float y0 = 0.f, y1 = 0.f;
  __syncthreads();
  const float beffv = consL[2176];

  // prologue: step-0 layer1 (h1_old = 0 -> no dots)
  {
    float x0 = input[row0 * T_IN], x1 = input[row1 * T_IN];
    if (kq == 0) {
      float b0 = consL[idx], b2v = consL[256 + idx], b3v = consL[384 + idx];
      float w0 = consL[1536 + idx], w2w = consL[1792 + idx],
            w3w = consL[1920 + idx];
      {
        float ig = fsigm(b0 + x0 * w0);
        float gg = ftanh(b2v + x0 * w2w), og = fsigm(b3v + x0 * w3w);
        c1a = ig * gg; h1b[0][0][idx] = (f16)(og * ftanh(c1a));
      }
      {
        float ig = fsigm(b0 + x1 * w0);
        float gg = ftanh(b2v + x1 * w2w), og = fsigm(b3v + x1 * w3w);
        c1b = ig * gg; h1b[0][1][idx] = (f16)(og * ftanh(c1b));
      }
    }
    __syncthreads();
  }

  // ring prologue: slots 0..7 of the 64-slot per-step stream
  uint4 ring[8];
#pragma unroll
  for (int c = 0; c < 8; ++c) ring[c] = Wp[c * 512];

  for (int s = 0; s < T_TOT; ++s) {
    const int par = s & 1;
    const int xi = (s + 1 < T_IN) ? (s + 1) : 0;
    float xl0 = input[row0 * T_IN + xi];
    float xl1 = input[row1 * T_IN + xi];

    const uint4* hL2r0 = (kq < 2)
        ? (const uint4*)&h1b[par][0][0] + kq * 8
        : (const uint4*)&h2b[par ^ 1][0][0] + (kq - 2) * 8;
    const uint4* hL2r1 = (kq < 2)
        ? (const uint4*)&h1b[par][1][0] + kq * 8
        : (const uint4*)&h2b[par ^ 1][1][0] + (kq - 2) * 8;
    const uint4* h3r0 = (const uint4*)&h3b[0][0] + kq * 4;
    const uint4* h3r1 = (const uint4*)&h3b[1][0] + kq * 4;

    float a2r0[4] = {0, 0, 0, 0}, a2r1[4] = {0, 0, 0, 0};
    float a3r0[4] = {0, 0, 0, 0}, a3r1[4] = {0, 0, 0, 0};

    // ---- P_A: L2 dots (32 u4, ring) + L3-early dots (16 u4, ring) ----
    uint4 E0, E1;
#pragma unroll
    for (int q = 0; q < 8; ++q) {
      uint4 H0 = hL2r0[q], H1 = hL2r1[q];
      u32 e0[4] = {H0.x, H0.y, H0.z, H0.w};
      u32 e1[4] = {H1.x, H1.y, H1.z, H1.w};
      if ((q & 1) == 0) { E0 = h3r0[q >> 1]; E1 = h3r1[q >> 1]; }
#pragma unroll
      for (int m = 0; m < 4; ++m) {
        const int sl = 6 * q + m;  // compile-time slot
        uint4 w = ring[sl & 7];
        ring[sl & 7] = Wp[((sl + 8) & 63) * 512];
        DOT4(a2r0, w, e0[m]);
        DOT4(a2r1, w, e1[m]);
      }
      {
        const int sl = 6 * q + 4;
        uint4 w = ring[sl & 7];
        ring[sl & 7] = Wp[((sl + 8) & 63) * 512];
        u32 h0 = (q & 1) ? E0.z : E0.x, h1v = (q & 1) ? E1.z : E1.x;
        DOT4(a3r0, w, h0);
        DOT4(a3r1, w, h1v);
      }
      {
        const int sl = 6 * q + 5;
        uint4 w = ring[sl & 7];
        ring[sl & 7] = Wp[((sl + 8) & 63) * 512];
        u32 h0 = (q & 1) ? E0.w : E0.y, h1v = (q & 1) ? E1.w : E1.y;
        DOT4(a3r0, w, h0);
        DOT4(a3r1, w, h1v);
      }
    }

    // L2 finish
#pragma unroll
    for (int g = 0; g < 4; ++g) {
      a2r0[g] += __shfl_xor(a2r0[g], 1, 64); a2r0[g] += __shfl_xor(a2r0[g], 2, 64);
      a2r1[g] += __shfl_xor(a2r1[g], 1, 64); a2r1[g] += __shfl_xor(a2r1[g], 2, 64);
    }
    if (kq == 0) {
      float b0 = consL[512 + idx], b1v = consL[640 + idx],
            b2v = consL[768 + idx], b3v = consL[896 + idx];
      {
        float ig = fsigm(a2r0[0] + b0), fg = fsigm(a2r0[1] + b1v);
        float gg = ftanh(a2r0[2] + b2v), og = fsigm(a2r0[3] + b3v);
        c2a = fg * c2a + ig * gg;
        h2b[par][0][idx] = (f16)(og * ftanh(c2a));
      }
      {
        float ig = fsigm(a2r1[0] + b0), fg = fsigm(a2r1[1] + b1v);
        float gg = ftanh(a2r1[2] + b2v), og = fsigm(a2r1[3] + b3v);
        c2b = fg * c2b + ig * gg;
        h2b[par][1][idx] = (f16)(og * ftanh(c2b));
      }
    }
    asm volatile("s_waitcnt lgkmcnt(0)\n\ts_barrier" ::: "memory");  // barrier1

    // ---- P_B: L3-late dots (16 u4, ring) + L1 dots for step s+1 (16 u4, LDS) ----
    const uint4* hLTr0 = (const uint4*)&h2b[par][0][0] + kq * 4;
    const uint4* hLTr1 = (const uint4*)&h2b[par][1][0] + kq * 4;
    const uint4* h1r0 = (const uint4*)&h1b[par][0][0] + kq * 4;
    const uint4* h1r1 = (const uint4*)&h1b[par][1][0] + kq * 4;

    float a1r0[4] = {0, 0, 0, 0}, a1r1[4] = {0, 0, 0, 0};
    uint4 L0, L1v, F0, F1;
#pragma unroll
    for (int q = 0; q < 8; ++q) {
      if ((q & 1) == 0) {
        L0 = hLTr0[q >> 1]; L1v = hLTr1[q >> 1];
        F0 = h1r0[q >> 1];  F1 = h1r1[q >> 1];
      }
      {
        const int sl = 48 + 2 * q;
        uint4 w = ring[sl & 7];
        ring[sl & 7] = Wp[((sl + 8) & 63) * 512];
        u32 h0 = (q & 1) ? L0.z : L0.x, h1x = (q & 1) ? L1v.z : L1v.x;
        DOT4(a3r0, w, h0);
        DOT4(a3r1, w, h1x);
      }
      {
        const int sl = 48 + 2 * q + 1;
        uint4 w = ring[sl & 7];
        ring[sl & 7] = Wp[((sl + 8) & 63) * 512];
        u32 h0 = (q & 1) ? L0.w : L0.y, h1x = (q & 1) ? L1v.w : L1v.y;
        DOT4(a3r0, w, h0);
        DOT4(a3r1, w, h1x);
      }
      {
        uint4 w = w1p[(2 * q) * 512];
        u32 h0 = (q & 1) ? F0.z : F0.x, h1x = (q & 1) ? F1.z : F1.x;
        DOT4(a1r0, w, h0);
        DOT4(a1r1, w, h1x);
      }
      {
        uint4 w = w1p[(2 * q + 1) * 512];
        u32 h0 = (q & 1) ? F0.w : F0.y, h1x = (q & 1) ? F1.w : F1.y;
        DOT4(a1r0, w, h0);
        DOT4(a1r1, w, h1x);
      }
    }

#pragma unroll
    for (int g = 0; g < 4; ++g) {
      a3r0[g] += __shfl_xor(a3r0[g], 1, 64); a3r0[g] += __shfl_xor(a3r0[g], 2, 64);
      a3r1[g] += __shfl_xor(a3r1[g], 1, 64); a3r1[g] += __shfl_xor(a3r1[g], 2, 64);
      a1r0[g] += __shfl_xor(a1r0[g], 1, 64); a1r0[g] += __shfl_xor(a1r0[g], 2, 64);
      a1r1[g] += __shfl_xor(a1r1[g], 1, 64); a1r1[g] += __shfl_xor(a1r1[g], 2, 64);
    }

    // L3 finish + head partial
    float p0 = 0.f, p1 = 0.f;
    if (kq == 0) {
      float b0 = consL[1024 + idx], b1v = consL[1152 + idx],
            b2v = consL[1280 + idx], b3v = consL[1408 + idx];
      float weffr = consL[2048 + idx];
      {
        float ig = fsigm(a3r0[0] + b0), fg = fsigm(a3r0[1] + b1v);
        float gg = ftanh(a3r0[2] + b2v), og = fsigm(a3r0[3] + b3v);
        c3a = fg * c3a + ig * gg;
        float h3 = og * ftanh(c3a);
        h3b[0][idx] = (f16)h3;
        p0 = weffr * h3;
      }
      {
        float ig = fsigm(a3r1[0] + b0), fg = fsigm(a3r1[1] + b1v);
        float gg = ftanh(a3r1[2] + b2v), og = fsigm(a3r1[3] + b3v);
        c3b = fg * c3b + ig * gg;
        float h3 = og * ftanh(c3b);
        h3b[1][idx] = (f16)h3;
        p1 = weffr * h3;
      }
    }
#pragma unroll
    for (int k = 1; k < 64; k <<= 1) {
      p0 += __shfl_xor(p0, k, 64);
      p1 += __shfl_xor(p1, k, 64);
    }
    if ((t & 63) == 0) { redp[0][t >> 6] = p0; redp[1][t >> 6] = p1; }
    asm volatile("s_waitcnt lgkmcnt(0)\n\ts_barrier" ::: "memory");  // barrier2

    y0 = beffv; y1 = beffv;
#pragma unroll
    for (int w8 = 0; w8 < 8; ++w8) { y0 += redp[0][w8]; y1 += redp[1][w8]; }
    if (t == 0) out[row0 * T_TOT + s] = y0;
    else if (t == 1) out[row1 * T_TOT + s] = y1;

    // L1 finish for step s+1
    float xv0 = (s + 1 < T_IN) ? xl0 : y0;
    float xv1 = (s + 1 < T_IN) ? xl1 : y1;
    if (kq == 0) {
      float b0 = consL[idx], b1v = consL[128 + idx], b2v = consL[256 + idx],
            b3v = consL[384 + idx];
      float w0 = consL[1536 + idx], w1w = consL[1664 + idx],
            w2w = consL[1792 + idx], w3w = consL[1920 + idx];
      {
        float ig = fsigm(a1r0[0] + b0 + xv0 * w0), fg = fsigm(a1r0[1] + b1v + xv0 * w1w);
        float gg = ftanh(a1r0[2] + b2v + xv0 * w2w), og = fsigm(a1r0[3] + b3v + xv0 * w3w);
        c1a = fg * c1a + ig * gg;
        h1b[par ^ 1][0][idx] = (f16)(og * ftanh(c1a));
      }
      {
        float ig = fsigm(a1r1[0] + b0 + xv1 * w0), fg = fsigm(a1r1[1] + b1v + xv1 * w1w);
        float gg = ftanh(a1r1[2] + b2v + xv1 * w2w), og = fsigm(a1r1[3] + b3v + xv1 * w3w);
        c1b = fg * c1b + ig * gg;
        h1b[par ^ 1][1][idx] = (f16)(og * ftanh(c1b));
      }
    }
    asm volatile("s_waitcnt lgkmcnt(0)\n\ts_barrier" ::: "memory");  // barrier3
  }
}

// ---- launch ---------------------------------------------------------------
extern "C" void kernel_launch(void* const* d_in, const int* in_sizes, int n_in,
                              void* d_out, int out_size, void* d_ws, size_t ws_size,
                              hipStream_t stream) {
  const float* input = (const float*)d_in[0];
  const float* Wih1 = (const float*)d_in[2];
  const float* Whh1 = (const float*)d_in[3];
  const float* bih1 = (const float*)d_in[4];
  const float* bhh1 = (const float*)d_in[5];
  const float* Wih2 = (const float*)d_in[6];
  const float* Whh2 = (const float*)d_in[7];
  const float* bih2 = (const float*)d_in[8];
  const float* bhh2 = (const float*)d_in[9];
  const float* Wih3 = (const float*)d_in[10];
  const float* Whh3 = (const float*)d_in[11];
  const float* bih3 = (const float*)d_in[12];
  const float* bhh3 = (const float*)d_in[13];
  const float* in_proj_w = (const float*)d_in[14];
  const float* in_proj_b = (const float*)d_in[15];
  const float* out_w = (const float*)d_in[16];
  const float* out_b = (const float*)d_in[17];
  const float* lin_w = (const float*)d_in[18];
  const float* lin_b = (const float*)d_in[19];

  char* ws = (char*)d_ws;
  u32* WT1s = (u32*)(ws + (0 << 10));   // 128 KB stream-order L1
  u32* WS = (u32*)(ws + (128 << 10));   // 512 KB combined L2+L3 stream
  float* consG = (float*)(ws + (640 << 10));  // ~8.7 KB

  pack1s<<<128, 256, 0, stream>>>(WT1s, Whh1);
  pack_stream<<<512, 256, 0, stream>>>(WS, Wih2, Whh2, Wih3, Whh3);
  prep_cons<<<8, 256, 0, stream>>>(consG, bih1, bhh1, bih2, bhh2, bih3, bhh3, Wih1);
  head_fold<<<1, 128, 0, stream>>>(consG, lin_w, out_w,
                                   in_proj_w + 2 * 128 * 128, in_proj_b + 256,
                                   out_b, lin_b);

  pendulum_persist<<<NBLK, 512, 0, stream>>>(
      input, (const uint4*)WT1s, (const uint4*)WS, consG, (float*)d_out);
}